// Round 10
// baseline (340.933 us; speedup 1.0000x reference)
//
#include <hip/hip_runtime.h>

#define NB 8
#define NT 30000
#define NL 6
#define NC 32
#define NHID 256

typedef _Float16 f16;
typedef f16 half8 __attribute__((ext_vector_type(8)));
typedef f16 half4v __attribute__((ext_vector_type(4)));
typedef f16 half2v __attribute__((ext_vector_type(2)));
typedef float floatx4 __attribute__((ext_vector_type(4)));

#define C_ELEMS (25165824ull)   // 8*6*128*128*32
#define NCONV   12288           // C_ELEMS / 8 / 256

// Weight image layout (f16 element offsets)
#define OFF_W0A  0       // 8192 : blk0_w0, permrow rows, b128 chunk c -> c ^ (m&7)
#define OFF_WA   8192    // 9216 : 9 small mats, b128 chunk c -> c ^ ((m>>1)&3)
#define OFF_HB   17408   // 1024 : hidden {w0,w1,w2,b} rows
#define OFF_FOLD 18432   // 128  : {M0,M1,M2,v+b0b1}
#define OFF_F32  18560   // 642  : float region (321 floats)
#define IMG_F16  19456   // padded; 38912 B = 2432 x 16 B
// float region offsets (in floats): b0b0[0..31], fow[32..63], bb0[64..191],
//                                   bb1[192..319], fob[320]

__device__ __align__(16) f16 g_chalf[C_ELEMS];
__device__ __align__(16) f16 g_img[IMG_F16];

// Row permutation so MFMA D-layout lands in "lane(q) owns channels 8q..8q+7" order.
__device__ __forceinline__ int permrow(int m) {
    return 8 * ((m & 15) >> 2) + 4 * (m >> 4) + (m & 3);
}

__device__ __forceinline__ half2v cvt2(float a, float b) {
    return __builtin_bit_cast(half2v, __builtin_amdgcn_cvt_pkrtz(a, b));
}

__device__ __forceinline__ half8 pack8(floatx4 f0, floatx4 f1) {
    half2v h0 = cvt2(f0[0], f0[1]), h1 = cvt2(f0[2], f0[3]);
    half2v h2 = cvt2(f1[0], f1[1]), h3 = cvt2(f1[2], f1[3]);
    half4v q0 = __builtin_shufflevector(h0, h1, 0, 1, 2, 3);
    half4v q1 = __builtin_shufflevector(h2, h3, 0, 1, 2, 3);
    return __builtin_shufflevector(q0, q1, 0, 1, 2, 3, 4, 5, 6, 7);
}

// relu + pack two floatx4 -> half8, register-only
__device__ __forceinline__ half8 relupack2(floatx4 a, floatx4 b) {
    half2v p0 = cvt2(fmaxf(a[0], 0.f), fmaxf(a[1], 0.f));
    half2v p1 = cvt2(fmaxf(a[2], 0.f), fmaxf(a[3], 0.f));
    half2v p2 = cvt2(fmaxf(b[0], 0.f), fmaxf(b[1], 0.f));
    half2v p3 = cvt2(fmaxf(b[2], 0.f), fmaxf(b[3], 0.f));
    half4v q0 = __builtin_shufflevector(p0, p1, 0, 1, 2, 3);
    half4v q1 = __builtin_shufflevector(p2, p3, 0, 1, 2, 3);
    return __builtin_shufflevector(q0, q1, 0, 1, 2, 3, 4, 5, 6, 7);
}

__device__ __forceinline__ half8 zext4(half4v lo) {
    const half4v zh = {};
    return __builtin_shufflevector(lo, zh, 0, 1, 2, 3, 4, 5, 6, 7);
}

__device__ __forceinline__ half8 splat8(float w) {
    f16 h = (f16)w;
    half8 v = {h, h, h, h, h, h, h, h};
    return v;
}

// Blocks 0..NCONV-1: c (f32) -> f16. Block NCONV: build the weight image.
__global__ __launch_bounds__(256) void convert_prep(
    const float* __restrict__ c,
    const float* __restrict__ fpw, const float* __restrict__ fpb,
    const float* __restrict__ b0w0, const float* __restrict__ b0b0,
    const float* __restrict__ b0w1, const float* __restrict__ b0b1,
    const float* __restrict__ b0ws, const float* __restrict__ bw0,
    const float* __restrict__ bb0, const float* __restrict__ bw1,
    const float* __restrict__ bb1, const float* __restrict__ fow,
    const float* __restrict__ fob)
{
    __shared__ floatx4 sp[8][32];
    const int tid = threadIdx.x;
    if (blockIdx.x < NCONV) {
        size_t i = ((size_t)blockIdx.x * 256 + tid) * 8;
        floatx4 f0 = *(const floatx4*)(c + i);
        floatx4 f1 = *(const floatx4*)(c + i + 4);
        *(half8*)(g_chalf + i) = pack8(f0, f1);
        return;
    }
    // ---- prep block ----
    {   // fold partials: channel i = tid&31, k-slice kc = tid>>5
        int i = tid & 31, kc = tid >> 5;
        const float* wrow = b0ws + i * 256 + kc * 32;
        const float* pw = fpw + kc * 96;
        const float* pb = fpb + kc * 32;
        floatx4 acc = {};
        #pragma unroll 8
        for (int k = 0; k < 32; k++) {
            float w = wrow[k];
            acc[0] = fmaf(w, pw[k * 3 + 0], acc[0]);
            acc[1] = fmaf(w, pw[k * 3 + 1], acc[1]);
            acc[2] = fmaf(w, pw[k * 3 + 2], acc[2]);
            acc[3] = fmaf(w, pb[k], acc[3]);
        }
        sp[kc][i] = acc;
    }
    __syncthreads();
    {   // w0A: row m = tid>>3, seg = tid&7 -> 4 b128 chunks, slot = chunk ^ (m&7)
        int m = tid >> 3, seg = tid & 7;
        const float* src = b0w0 + permrow(m) * 256 + seg * 32;
        f16* dst = g_img + OFF_W0A + m * 256;
        int sw = m & 7;
        #pragma unroll
        for (int ci = 0; ci < 4; ci++) {
            int cidx = seg * 4 + ci;
            floatx4 f0 = *(const floatx4*)(src + ci * 8);
            floatx4 f1 = *(const floatx4*)(src + ci * 8 + 4);
            *(half8*)(dst + ((cidx ^ sw) << 3)) = pack8(f0, f1);
        }
    }
    // wA: 9 mats x 32 rows; 4 b128 chunks per row at slot c ^ ((m>>1)&3)
    for (int r = tid; r < 288; r += 256) {
        int mi = r >> 5, m = r & 31;
        int pm = permrow(m);
        const float* src;
        if (mi == 0) src = b0w1 + pm * 32;
        else {
            int mat = mi - 1, bi = mat >> 1;
            src = ((mat & 1) ? bw1 : bw0) + (bi * 32 + pm) * 32;
        }
        f16* dst = g_img + OFF_WA + mi * 1024 + m * 32;
        int sw = (m >> 1) & 3;
        #pragma unroll
        for (int ci = 0; ci < 4; ci++) {
            floatx4 f0 = *(const floatx4*)(src + ci * 8);
            floatx4 f1 = *(const floatx4*)(src + ci * 8 + 4);
            *(half8*)(dst + ((ci ^ sw) << 3)) = pack8(f0, f1);
        }
    }
    {   // hB: row tid = (cch,m) holds hidden h = cch*32 + permrow(m)
        int cch = tid >> 5, m = tid & 31;
        int h = cch * 32 + permrow(m);
        half2v a = cvt2(fpw[h * 3 + 0], fpw[h * 3 + 1]);
        half2v bq = cvt2(fpw[h * 3 + 2], fpb[h]);
        *(half4v*)(g_img + OFF_HB + tid * 4) = __builtin_shufflevector(a, bq, 0, 1, 2, 3);
    }
    float* fimg = (float*)(g_img + OFF_F32);
    if (tid < 32) {   // fold reduce + biases
        int pm = permrow(tid);
        floatx4 s = sp[0][pm];
        #pragma unroll
        for (int j = 1; j < 8; j++) s += sp[j][pm];
        half2v a = cvt2(s[0], s[1]);
        half2v bq = cvt2(s[2], s[3] + b0b1[pm]);
        *(half4v*)(g_img + OFF_FOLD + tid * 4) = __builtin_shufflevector(a, bq, 0, 1, 2, 3);
        fimg[tid] = b0b0[tid];
        fimg[32 + tid] = fow[tid];
    }
    if (tid >= 64 && tid < 192) {
        fimg[tid] = bb0[tid - 64];         // bb0 at [64..191]
        fimg[tid + 128] = bb1[tid - 64];   // bb1 at [192..319]
    }
    if (tid == 0) fimg[320] = fob[0];
}

// (256, 2): unified arch+acc register cap 256. Natural footprint is ~120-200;
// any cap <= 168 (>=3 waves/SIMD) spills 170-340 MB of scratch (r3-r5, r9).
__global__ __launch_bounds__(256, 2) void decoder_kernel(
    const float* __restrict__ p, const float* __restrict__ Cm,
    float* __restrict__ out)
{
    __shared__ __align__(16) f16 s_img[IMG_F16];   // 38912 B
    __shared__ float s_cam[NL][8];

    const int tid = threadIdx.x;
    // XCD swizzle: b = id & 7 -> all blocks of a batch share one XCD's L2
    const int b = blockIdx.x & 7;
    const int tile = blockIdx.x >> 3;

    // ---- staging: straight 16B copy of the prebuilt image ----
    {
        const uint4* gsrc = (const uint4*)g_img;
        uint4* ldst = (uint4*)s_img;
        for (int i = tid; i < IMG_F16 / 8; i += 256) ldst[i] = gsrc[i];
    }
    if (tid >= 192 && tid < 192 + NL) {
        int l = tid - 192;
        const float* cm = Cm + ((size_t)b * NL + l) * 12;
        float denom = cm[9] + 0.05f;
        float s = 63.5f / (0.55f * denom);
        s_cam[l][0] = cm[0] * s; s_cam[l][1] = cm[1] * s; s_cam[l][2] = cm[2] * s;
        s_cam[l][3] = cm[3] * s; s_cam[l][4] = cm[4] * s; s_cam[l][5] = cm[5] * s;
    }
    __syncthreads();

    const int lane = tid & 63;
    const int wv = tid >> 6;
    const int q = lane >> 4;
    const int i16 = lane & 15;
    const int sw0 = i16 & 7;

    const f16* s_w0A = s_img + OFF_W0A;
    const f16* s_wA  = s_img + OFF_WA;
    const f16* s_hB  = s_img + OFF_HB;
    const float* sf  = (const float*)(s_img + OFF_F32);

    const f16* w0r0 = s_w0A + i16 * 256;
    const f16* w0r1 = s_w0A + (16 + i16) * 256;
    const int qsw = (q ^ ((i16 >> 1) & 3)) << 3;
    const int soff0 = i16 * 32 + qsw;
    const int soff1 = (16 + i16) * 32 + qsw;
    const f16* hB0 = s_hB + i16 * 4;
    const f16* hB1 = s_hB + (16 + i16) * 4;
    const f16* cqh = g_chalf + (((size_t)b * NL) << 19) + q * 8;

    const half8 fA0 = zext4(*(const half4v*)(s_img + OFF_FOLD + i16 * 4));
    const half8 fA1 = zext4(*(const half4v*)(s_img + OFF_FOLD + (16 + i16) * 4));
    const floatx4 fw0 = *(const floatx4*)&sf[32 + q * 8];
    const floatx4 fw1 = *(const floatx4*)&sf[32 + q * 8 + 4];
    const floatx4 b00a = *(const floatx4*)&sf[q * 8];
    const floatx4 b00b = *(const floatx4*)&sf[q * 8 + 4];
    const float fobv = sf[320];

    #pragma unroll 1
    for (int g = 0; g < 2; g++) {
        const int t = tile * 128 + (g * 4 + wv) * 16 + i16;
        const int tc = min(t, NT - 1);
        const float* pp = p + ((size_t)b * NT + tc) * 3;
        float px = pp[0], py = pp[1], pz = pp[2];

        // ---- bilinear gather, 3-phase: all addresses -> ALL 24 loads in
        // flight -> accumulate. Removes the 6 sequential vmcnt drains of the
        // per-view loop (the r8 structure's exposed-latency term). ----
        int idxs[NL][4];
        float wgts[NL][4];
        #pragma unroll
        for (int l = 0; l < NL; l++) {
            float x = s_cam[l][0] * px + s_cam[l][1] * py + s_cam[l][2] * pz + 63.5f;
            float y = s_cam[l][3] * px + s_cam[l][4] * py + s_cam[l][5] * pz + 63.5f;
            float x0f = floorf(x), x1f = ceilf(x);
            float y0f = floorf(y), y1f = ceilf(y);
            float dxw = x1f - x, dyw = y1f - y;
            int x0 = min(max((int)x0f, 0), 127);
            int x1 = min(max((int)x1f, 0), 127);
            int y0 = min(max((int)y0f, 0), 127);
            int y1 = min(max((int)y1f, 0), 127);
            idxs[l][0] = (x0 << 7) + y0;
            idxs[l][1] = (x1 << 7) + y0;
            idxs[l][2] = (x0 << 7) + y1;
            idxs[l][3] = (x1 << 7) + y1;
            wgts[l][0] = dxw * dyw;
            wgts[l][1] = (1.f - dxw) * dyw;
            wgts[l][2] = dxw * (1.f - dyw);
            wgts[l][3] = (1.f - dxw) * (1.f - dyw);
        }
        half8 tv[NL][4];
        #pragma unroll
        for (int l = 0; l < NL; l++) {
            const f16* base = cqh + ((size_t)l << 19);
            #pragma unroll
            for (int k = 0; k < 4; k++)
                tv[l][k] = *(const half8*)(base + (size_t)idxs[l][k] * 32);
        }
        half8 feh = {};
        #pragma unroll
        for (int l = 0; l < NL; l++)
            #pragma unroll
            for (int k = 0; k < 4; k++)
                feh += tv[l][k] * splat8(wgts[l][k]);
        floatx4 fe0 = floatx4{(float)feh[0], (float)feh[1], (float)feh[2], (float)feh[3]};
        floatx4 fe1 = floatx4{(float)feh[4], (float)feh[5], (float)feh[6], (float)feh[7]};

        // ---- B operand for K=4 projections (rows 0..3 live on quad 0) ----
        half8 bp;
        {
            half2v xy = cvt2(px, py), z1 = cvt2(pz, 1.0f);
            half4v lo = __builtin_shufflevector(xy, z1, 0, 1, 2, 3);
            half8 full = zext4(lo);
            const half8 zh8 = {};
            bp = (q == 0) ? full : zh8;
        }

        // ---- blk0: hidden layer (via MFMA) + 256->32 ----
        floatx4 acc0 = b00a, acc1 = b00b;
        #pragma unroll 2
        for (int cch = 0; cch < 8; cch++) {
            half8 ha = zext4(*(const half4v*)(hB0 + cch * 128));
            half8 hb = zext4(*(const half4v*)(hB1 + cch * 128));
            floatx4 hz = {};
            floatx4 h0 = __builtin_amdgcn_mfma_f32_16x16x32_f16(ha, bp, hz, 0, 0, 0);
            floatx4 h1 = __builtin_amdgcn_mfma_f32_16x16x32_f16(hb, bp, hz, 0, 0, 0);
            half8 bf = relupack2(h0, h1);
            half8 a0 = *(const half8*)(w0r0 + ((((cch << 2) | q) ^ sw0) << 3));
            half8 a1 = *(const half8*)(w0r1 + ((((cch << 2) | q) ^ sw0) << 3));
            acc0 = __builtin_amdgcn_mfma_f32_16x16x32_f16(a0, bf, acc0, 0, 0, 0);
            acc1 = __builtin_amdgcn_mfma_f32_16x16x32_f16(a1, bf, acc1, 0, 0, 0);
        }

        // ---- st = fold(p)+b0b1 (MFMA, C=feat) + W1 @ relu(acc) ----
        floatx4 st0 = __builtin_amdgcn_mfma_f32_16x16x32_f16(fA0, bp, fe0, 0, 0, 0);
        floatx4 st1 = __builtin_amdgcn_mfma_f32_16x16x32_f16(fA1, bp, fe1, 0, 0, 0);
        {
            half8 bf = relupack2(acc0, acc1);
            half8 a0 = *(const half8*)(s_wA + soff0);
            half8 a1 = *(const half8*)(s_wA + soff1);
            st0 = __builtin_amdgcn_mfma_f32_16x16x32_f16(a0, bf, st0, 0, 0, 0);
            st1 = __builtin_amdgcn_mfma_f32_16x16x32_f16(a1, bf, st1, 0, 0, 0);
        }

        // ---- residual blocks ----
        #pragma unroll
        for (int bk = 0; bk < 4; bk++) {
            const f16* w_a = s_wA + (1 + 2 * bk) * 1024;
            const f16* w_b = s_wA + (2 + 2 * bk) * 1024;
            floatx4 h0 = *(const floatx4*)&sf[64 + bk * 32 + q * 8];
            floatx4 h1 = *(const floatx4*)&sf[64 + bk * 32 + q * 8 + 4];
            {
                half8 bf = relupack2(st0, st1);
                half8 a0 = *(const half8*)(w_a + soff0);
                half8 a1 = *(const half8*)(w_a + soff1);
                h0 = __builtin_amdgcn_mfma_f32_16x16x32_f16(a0, bf, h0, 0, 0, 0);
                h1 = __builtin_amdgcn_mfma_f32_16x16x32_f16(a1, bf, h1, 0, 0, 0);
            }
            floatx4 d0 = *(const floatx4*)&sf[192 + bk * 32 + q * 8];
            floatx4 d1 = *(const floatx4*)&sf[192 + bk * 32 + q * 8 + 4];
            {
                half8 bf = relupack2(h0, h1);
                half8 a0 = *(const half8*)(w_b + soff0);
                half8 a1 = *(const half8*)(w_b + soff1);
                d0 = __builtin_amdgcn_mfma_f32_16x16x32_f16(a0, bf, d0, 0, 0, 0);
                d1 = __builtin_amdgcn_mfma_f32_16x16x32_f16(a1, bf, d1, 0, 0, 0);
            }
            st0 += d0 + fe0;
            st1 += d1 + fe1;
        }

        // ---- head ----
        float o = 0.f;
        #pragma unroll
        for (int r = 0; r < 4; r++)
            o += fmaxf(st0[r], 0.f) * fw0[r] + fmaxf(st1[r], 0.f) * fw1[r];
        o += __shfl_xor(o, 16);
        o += __shfl_xor(o, 32);
        if (q == 0 && t < NT) out[(size_t)b * NT + t] = o + fobv;
    }
}

extern "C" void kernel_launch(void* const* d_in, const int* in_sizes, int n_in,
                              void* d_out, int out_size, void* d_ws, size_t ws_size,
                              hipStream_t stream) {
    const float* p    = (const float*)d_in[0];
    const float* c    = (const float*)d_in[2];
    const float* Cm   = (const float*)d_in[3];
    const float* fpw  = (const float*)d_in[4];
    const float* fpb  = (const float*)d_in[5];
    const float* b0w0 = (const float*)d_in[6];
    const float* b0b0 = (const float*)d_in[7];
    const float* b0w1 = (const float*)d_in[8];
    const float* b0b1 = (const float*)d_in[9];
    const float* b0ws = (const float*)d_in[10];
    const float* bw0  = (const float*)d_in[11];
    const float* bb0  = (const float*)d_in[12];
    const float* bw1  = (const float*)d_in[13];
    const float* bb1  = (const float*)d_in[14];
    const float* fow  = (const float*)d_in[15];
    const float* fob  = (const float*)d_in[16];

    convert_prep<<<NCONV + 1, 256, 0, stream>>>(c, fpw, fpb, b0w0, b0b0, b0w1, b0b1,
                                                b0ws, bw0, bb0, bw1, bb1, fow, fob);

    dim3 grid(((NT + 127) / 128) * NB);  // 1880, 1-D for XCD swizzle
    decoder_kernel<<<grid, 256, 0, stream>>>(p, Cm, (float*)d_out);
}

// Round 11
// 254.856 us; speedup vs baseline: 1.3378x; 1.3378x over previous
//
#include <hip/hip_runtime.h>

#define NB 8
#define NT 30000
#define NL 6
#define NC 32
#define NHID 256

typedef _Float16 f16;
typedef f16 half8 __attribute__((ext_vector_type(8)));
typedef f16 half4v __attribute__((ext_vector_type(4)));
typedef f16 half2v __attribute__((ext_vector_type(2)));
typedef float floatx4 __attribute__((ext_vector_type(4)));

#define C_ELEMS (25165824ull)   // 8*6*128*128*32
#define NCONV   12288           // C_ELEMS / 8 / 256
#define FEAT_ELEMS (7680000ull) // 8*30000*32

// Weight image layout (f16 element offsets)
#define OFF_W0A  0       // 8192 : blk0_w0, permrow rows, b128 chunk c -> c ^ (m&7)
#define OFF_WA   8192    // 9216 : 9 small mats, b128 chunk c -> c ^ ((m>>1)&3)
#define OFF_HB   17408   // 1024 : hidden {w0,w1,w2,b} rows
#define OFF_FOLD 18432   // 128  : {M0,M1,M2,v+b0b1}
#define OFF_F32  18560   // 642  : float region (321 floats)
#define IMG_F16  19456   // padded; 38912 B = 2432 x 16 B
// float region offsets (floats): b0b0[0..31], fow[32..63], bb0[64..191],
//                                bb1[192..319], fob[320]

__device__ __align__(16) f16 g_chalf[C_ELEMS];
__device__ __align__(16) f16 g_feat[FEAT_ELEMS];
__device__ __align__(16) f16 g_img[IMG_F16];

__device__ __forceinline__ int permrow(int m) {
    return 8 * ((m & 15) >> 2) + 4 * (m >> 4) + (m & 3);
}

__device__ __forceinline__ half2v cvt2(float a, float b) {
    return __builtin_bit_cast(half2v, __builtin_amdgcn_cvt_pkrtz(a, b));
}

__device__ __forceinline__ half8 pack8(floatx4 f0, floatx4 f1) {
    half2v h0 = cvt2(f0[0], f0[1]), h1 = cvt2(f0[2], f0[3]);
    half2v h2 = cvt2(f1[0], f1[1]), h3 = cvt2(f1[2], f1[3]);
    half4v q0 = __builtin_shufflevector(h0, h1, 0, 1, 2, 3);
    half4v q1 = __builtin_shufflevector(h2, h3, 0, 1, 2, 3);
    return __builtin_shufflevector(q0, q1, 0, 1, 2, 3, 4, 5, 6, 7);
}

__device__ __forceinline__ half8 relupack2(floatx4 a, floatx4 b) {
    half2v p0 = cvt2(fmaxf(a[0], 0.f), fmaxf(a[1], 0.f));
    half2v p1 = cvt2(fmaxf(a[2], 0.f), fmaxf(a[3], 0.f));
    half2v p2 = cvt2(fmaxf(b[0], 0.f), fmaxf(b[1], 0.f));
    half2v p3 = cvt2(fmaxf(b[2], 0.f), fmaxf(b[3], 0.f));
    half4v q0 = __builtin_shufflevector(p0, p1, 0, 1, 2, 3);
    half4v q1 = __builtin_shufflevector(p2, p3, 0, 1, 2, 3);
    return __builtin_shufflevector(q0, q1, 0, 1, 2, 3, 4, 5, 6, 7);
}

__device__ __forceinline__ half8 zext4(half4v lo) {
    const half4v zh = {};
    return __builtin_shufflevector(lo, zh, 0, 1, 2, 3, 4, 5, 6, 7);
}

__device__ __forceinline__ half8 splat8(float w) {
    f16 h = (f16)w;
    half8 v = {h, h, h, h, h, h, h, h};
    return v;
}

// Blocks 0..NCONV-1: c (f32) -> f16. Block NCONV: build the weight image.
__global__ __launch_bounds__(256) void convert_prep(
    const float* __restrict__ c,
    const float* __restrict__ fpw, const float* __restrict__ fpb,
    const float* __restrict__ b0w0, const float* __restrict__ b0b0,
    const float* __restrict__ b0w1, const float* __restrict__ b0b1,
    const float* __restrict__ b0ws, const float* __restrict__ bw0,
    const float* __restrict__ bb0, const float* __restrict__ bw1,
    const float* __restrict__ bb1, const float* __restrict__ fow,
    const float* __restrict__ fob)
{
    __shared__ floatx4 sp[8][32];
    const int tid = threadIdx.x;
    if (blockIdx.x < NCONV) {
        size_t i = ((size_t)blockIdx.x * 256 + tid) * 8;
        floatx4 f0 = *(const floatx4*)(c + i);
        floatx4 f1 = *(const floatx4*)(c + i + 4);
        *(half8*)(g_chalf + i) = pack8(f0, f1);
        return;
    }
    // ---- prep block ----
    {   // fold partials: channel i = tid&31, k-slice kc = tid>>5
        int i = tid & 31, kc = tid >> 5;
        const float* wrow = b0ws + i * 256 + kc * 32;
        const float* pw = fpw + kc * 96;
        const float* pb = fpb + kc * 32;
        floatx4 acc = {};
        #pragma unroll 8
        for (int k = 0; k < 32; k++) {
            float w = wrow[k];
            acc[0] = fmaf(w, pw[k * 3 + 0], acc[0]);
            acc[1] = fmaf(w, pw[k * 3 + 1], acc[1]);
            acc[2] = fmaf(w, pw[k * 3 + 2], acc[2]);
            acc[3] = fmaf(w, pb[k], acc[3]);
        }
        sp[kc][i] = acc;
    }
    __syncthreads();
    {   // w0A
        int m = tid >> 3, seg = tid & 7;
        const float* src = b0w0 + permrow(m) * 256 + seg * 32;
        f16* dst = g_img + OFF_W0A + m * 256;
        int sw = m & 7;
        #pragma unroll
        for (int ci = 0; ci < 4; ci++) {
            int cidx = seg * 4 + ci;
            floatx4 f0 = *(const floatx4*)(src + ci * 8);
            floatx4 f1 = *(const floatx4*)(src + ci * 8 + 4);
            *(half8*)(dst + ((cidx ^ sw) << 3)) = pack8(f0, f1);
        }
    }
    for (int r = tid; r < 288; r += 256) {
        int mi = r >> 5, m = r & 31;
        int pm = permrow(m);
        const float* src;
        if (mi == 0) src = b0w1 + pm * 32;
        else {
            int mat = mi - 1, bi = mat >> 1;
            src = ((mat & 1) ? bw1 : bw0) + (bi * 32 + pm) * 32;
        }
        f16* dst = g_img + OFF_WA + mi * 1024 + m * 32;
        int sw = (m >> 1) & 3;
        #pragma unroll
        for (int ci = 0; ci < 4; ci++) {
            floatx4 f0 = *(const floatx4*)(src + ci * 8);
            floatx4 f1 = *(const floatx4*)(src + ci * 8 + 4);
            *(half8*)(dst + ((ci ^ sw) << 3)) = pack8(f0, f1);
        }
    }
    {   // hB
        int cch = tid >> 5, m = tid & 31;
        int h = cch * 32 + permrow(m);
        half2v a = cvt2(fpw[h * 3 + 0], fpw[h * 3 + 1]);
        half2v bq = cvt2(fpw[h * 3 + 2], fpb[h]);
        *(half4v*)(g_img + OFF_HB + tid * 4) = __builtin_shufflevector(a, bq, 0, 1, 2, 3);
    }
    float* fimg = (float*)(g_img + OFF_F32);
    if (tid < 32) {
        int pm = permrow(tid);
        floatx4 s = sp[0][pm];
        #pragma unroll
        for (int j = 1; j < 8; j++) s += sp[j][pm];
        half2v a = cvt2(s[0], s[1]);
        half2v bq = cvt2(s[2], s[3] + b0b1[pm]);
        *(half4v*)(g_img + OFF_FOLD + tid * 4) = __builtin_shufflevector(a, bq, 0, 1, 2, 3);
        fimg[tid] = b0b0[tid];
        fimg[32 + tid] = fow[tid];
    }
    if (tid >= 64 && tid < 192) {
        fimg[tid] = bb0[tid - 64];
        fimg[tid + 128] = bb1[tid - 64];
    }
    if (tid == 0) fimg[320] = fob[0];
}

// ---- Kernel A: gather only. Tiny register footprint -> 4 waves/SIMD. ----
// XCD swizzle keeps each batch's 6 MB f16 slab resident in ONE XCD's L2
// (measured r8: per-XCD demand is ~0.5 TB/s vs ~4.3 TB/s L2 service - headroom).
__global__ __launch_bounds__(256, 4) void gather_kernel(
    const float* __restrict__ p, const float* __restrict__ Cm)
{
    __shared__ float s_cam[NL][8];
    const int tid = threadIdx.x;
    const int b = blockIdx.x & 7;
    const int tile = blockIdx.x >> 3;

    if (tid < NL) {
        const float* cm = Cm + ((size_t)b * NL + tid) * 12;
        float denom = cm[9] + 0.05f;
        float s = 63.5f / (0.55f * denom);
        s_cam[tid][0] = cm[0] * s; s_cam[tid][1] = cm[1] * s; s_cam[tid][2] = cm[2] * s;
        s_cam[tid][3] = cm[3] * s; s_cam[tid][4] = cm[4] * s; s_cam[tid][5] = cm[5] * s;
    }
    __syncthreads();

    const int lane = tid & 63;
    const int wv = tid >> 6;
    const int q = lane >> 4;
    const int i16 = lane & 15;
    const f16* cqh = g_chalf + (((size_t)b * NL) << 19) + q * 8;

    #pragma unroll 1
    for (int g = 0; g < 2; g++) {
        const int t = tile * 128 + (g * 4 + wv) * 16 + i16;
        const int tc = min(t, NT - 1);
        const float* pp = p + ((size_t)b * NT + tc) * 3;
        float px = pp[0], py = pp[1], pz = pp[2];

        half8 feh = {};
        #pragma unroll
        for (int l = 0; l < NL; l++) {
            float x = s_cam[l][0] * px + s_cam[l][1] * py + s_cam[l][2] * pz + 63.5f;
            float y = s_cam[l][3] * px + s_cam[l][4] * py + s_cam[l][5] * pz + 63.5f;
            float x0f = floorf(x), x1f = ceilf(x);
            float y0f = floorf(y), y1f = ceilf(y);
            float dxw = x1f - x, dyw = y1f - y;
            int x0 = min(max((int)x0f, 0), 127);
            int x1 = min(max((int)x1f, 0), 127);
            int y0 = min(max((int)y0f, 0), 127);
            int y1 = min(max((int)y1f, 0), 127);
            const f16* base = cqh + ((size_t)l << 19);
            half8 t11 = *(const half8*)(base + (size_t)((x0 << 7) + y0) * 32);
            half8 t12 = *(const half8*)(base + (size_t)((x1 << 7) + y0) * 32);
            half8 t21 = *(const half8*)(base + (size_t)((x0 << 7) + y1) * 32);
            half8 t22 = *(const half8*)(base + (size_t)((x1 << 7) + y1) * 32);
            float w11 = dxw * dyw;
            float w12 = (1.f - dxw) * dyw;
            float w21 = dxw * (1.f - dyw);
            float w22 = (1.f - dxw) * (1.f - dyw);
            feh += t11 * splat8(w11) + t12 * splat8(w12)
                 + t21 * splat8(w21) + t22 * splat8(w22);
        }
        if (t < NT)
            *(half8*)(g_feat + ((size_t)b * NT + t) * 32 + q * 8) = feh;
    }
}

// ---- Kernel B: MLP only. (256,2): unified arch+acc cap 256; caps <=168
// spilled 170-340 MB scratch in r3-r5/r9/r10. ----
__global__ __launch_bounds__(256, 2) void mlp_kernel(
    const float* __restrict__ p, float* __restrict__ out)
{
    __shared__ __align__(16) f16 s_img[IMG_F16];   // 38912 B
    const int tid = threadIdx.x;
    const int b = blockIdx.x & 7;
    const int tile = blockIdx.x >> 3;

    {
        const uint4* gsrc = (const uint4*)g_img;
        uint4* ldst = (uint4*)s_img;
        for (int i = tid; i < IMG_F16 / 8; i += 256) ldst[i] = gsrc[i];
    }
    __syncthreads();

    const int lane = tid & 63;
    const int wv = tid >> 6;
    const int q = lane >> 4;
    const int i16 = lane & 15;
    const int sw0 = i16 & 7;

    const f16* s_w0A = s_img + OFF_W0A;
    const f16* s_wA  = s_img + OFF_WA;
    const f16* s_hB  = s_img + OFF_HB;
    const float* sf  = (const float*)(s_img + OFF_F32);

    const f16* w0r0 = s_w0A + i16 * 256;
    const f16* w0r1 = s_w0A + (16 + i16) * 256;
    const int qsw = (q ^ ((i16 >> 1) & 3)) << 3;
    const int soff0 = i16 * 32 + qsw;
    const int soff1 = (16 + i16) * 32 + qsw;
    const f16* hB0 = s_hB + i16 * 4;
    const f16* hB1 = s_hB + (16 + i16) * 4;

    const half8 fA0 = zext4(*(const half4v*)(s_img + OFF_FOLD + i16 * 4));
    const half8 fA1 = zext4(*(const half4v*)(s_img + OFF_FOLD + (16 + i16) * 4));
    const floatx4 fw0 = *(const floatx4*)&sf[32 + q * 8];
    const floatx4 fw1 = *(const floatx4*)&sf[32 + q * 8 + 4];
    const floatx4 b00a = *(const floatx4*)&sf[q * 8];
    const floatx4 b00b = *(const floatx4*)&sf[q * 8 + 4];
    const float fobv = sf[320];

    #pragma unroll 1
    for (int g = 0; g < 2; g++) {
        const int t = tile * 128 + (g * 4 + wv) * 16 + i16;
        const int tc = min(t, NT - 1);
        const float* pp = p + ((size_t)b * NT + tc) * 3;
        float px = pp[0], py = pp[1], pz = pp[2];

        // feat: one coalesced b128 from the gather kernel's output
        half8 feh = *(const half8*)(g_feat + ((size_t)b * NT + tc) * 32 + q * 8);
        floatx4 fe0 = floatx4{(float)feh[0], (float)feh[1], (float)feh[2], (float)feh[3]};
        floatx4 fe1 = floatx4{(float)feh[4], (float)feh[5], (float)feh[6], (float)feh[7]};

        half8 bp;
        {
            half2v xy = cvt2(px, py), z1 = cvt2(pz, 1.0f);
            half4v lo = __builtin_shufflevector(xy, z1, 0, 1, 2, 3);
            half8 full = zext4(lo);
            const half8 zh8 = {};
            bp = (q == 0) ? full : zh8;
        }

        floatx4 acc0 = b00a, acc1 = b00b;
        #pragma unroll 2
        for (int cch = 0; cch < 8; cch++) {
            half8 ha = zext4(*(const half4v*)(hB0 + cch * 128));
            half8 hb = zext4(*(const half4v*)(hB1 + cch * 128));
            floatx4 hz = {};
            floatx4 h0 = __builtin_amdgcn_mfma_f32_16x16x32_f16(ha, bp, hz, 0, 0, 0);
            floatx4 h1 = __builtin_amdgcn_mfma_f32_16x16x32_f16(hb, bp, hz, 0, 0, 0);
            half8 bf = relupack2(h0, h1);
            half8 a0 = *(const half8*)(w0r0 + ((((cch << 2) | q) ^ sw0) << 3));
            half8 a1 = *(const half8*)(w0r1 + ((((cch << 2) | q) ^ sw0) << 3));
            acc0 = __builtin_amdgcn_mfma_f32_16x16x32_f16(a0, bf, acc0, 0, 0, 0);
            acc1 = __builtin_amdgcn_mfma_f32_16x16x32_f16(a1, bf, acc1, 0, 0, 0);
        }

        floatx4 st0 = __builtin_amdgcn_mfma_f32_16x16x32_f16(fA0, bp, fe0, 0, 0, 0);
        floatx4 st1 = __builtin_amdgcn_mfma_f32_16x16x32_f16(fA1, bp, fe1, 0, 0, 0);
        {
            half8 bf = relupack2(acc0, acc1);
            half8 a0 = *(const half8*)(s_wA + soff0);
            half8 a1 = *(const half8*)(s_wA + soff1);
            st0 = __builtin_amdgcn_mfma_f32_16x16x32_f16(a0, bf, st0, 0, 0, 0);
            st1 = __builtin_amdgcn_mfma_f32_16x16x32_f16(a1, bf, st1, 0, 0, 0);
        }

        #pragma unroll
        for (int bk = 0; bk < 4; bk++) {
            const f16* w_a = s_wA + (1 + 2 * bk) * 1024;
            const f16* w_b = s_wA + (2 + 2 * bk) * 1024;
            floatx4 h0 = *(const floatx4*)&sf[64 + bk * 32 + q * 8];
            floatx4 h1 = *(const floatx4*)&sf[64 + bk * 32 + q * 8 + 4];
            {
                half8 bf = relupack2(st0, st1);
                half8 a0 = *(const half8*)(w_a + soff0);
                half8 a1 = *(const half8*)(w_a + soff1);
                h0 = __builtin_amdgcn_mfma_f32_16x16x32_f16(a0, bf, h0, 0, 0, 0);
                h1 = __builtin_amdgcn_mfma_f32_16x16x32_f16(a1, bf, h1, 0, 0, 0);
            }
            floatx4 d0 = *(const floatx4*)&sf[192 + bk * 32 + q * 8];
            floatx4 d1 = *(const floatx4*)&sf[192 + bk * 32 + q * 8 + 4];
            {
                half8 bf = relupack2(h0, h1);
                half8 a0 = *(const half8*)(w_b + soff0);
                half8 a1 = *(const half8*)(w_b + soff1);
                d0 = __builtin_amdgcn_mfma_f32_16x16x32_f16(a0, bf, d0, 0, 0, 0);
                d1 = __builtin_amdgcn_mfma_f32_16x16x32_f16(a1, bf, d1, 0, 0, 0);
            }
            st0 += d0 + fe0;
            st1 += d1 + fe1;
        }

        float o = 0.f;
        #pragma unroll
        for (int r = 0; r < 4; r++)
            o += fmaxf(st0[r], 0.f) * fw0[r] + fmaxf(st1[r], 0.f) * fw1[r];
        o += __shfl_xor(o, 16);
        o += __shfl_xor(o, 32);
        if (q == 0 && t < NT) out[(size_t)b * NT + t] = o + fobv;
    }
}

extern "C" void kernel_launch(void* const* d_in, const int* in_sizes, int n_in,
                              void* d_out, int out_size, void* d_ws, size_t ws_size,
                              hipStream_t stream) {
    const float* p    = (const float*)d_in[0];
    const float* c    = (const float*)d_in[2];
    const float* Cm   = (const float*)d_in[3];
    const float* fpw  = (const float*)d_in[4];
    const float* fpb  = (const float*)d_in[5];
    const float* b0w0 = (const float*)d_in[6];
    const float* b0b0 = (const float*)d_in[7];
    const float* b0w1 = (const float*)d_in[8];
    const float* b0b1 = (const float*)d_in[9];
    const float* b0ws = (const float*)d_in[10];
    const float* bw0  = (const float*)d_in[11];
    const float* bb0  = (const float*)d_in[12];
    const float* bw1  = (const float*)d_in[13];
    const float* bb1  = (const float*)d_in[14];
    const float* fow  = (const float*)d_in[15];
    const float* fob  = (const float*)d_in[16];

    convert_prep<<<NCONV + 1, 256, 0, stream>>>(c, fpw, fpb, b0w0, b0b0, b0w1, b0b1,
                                                b0ws, bw0, bb0, bw1, bb1, fow, fob);

    dim3 grid(((NT + 127) / 128) * NB);  // 1880, 1-D for XCD swizzle
    gather_kernel<<<grid, 256, 0, stream>>>(p, Cm);
    mlp_kernel<<<grid, 256, 0, stream>>>(p, (float*)d_out);
}

// Round 12
// 252.376 us; speedup vs baseline: 1.3509x; 1.0098x over previous
//
#include <hip/hip_runtime.h>

#define NB 8
#define NT 30000
#define NL 6
#define NC 32
#define NHID 256

typedef _Float16 f16;
typedef f16 half8 __attribute__((ext_vector_type(8)));
typedef f16 half4v __attribute__((ext_vector_type(4)));
typedef f16 half2v __attribute__((ext_vector_type(2)));
typedef float floatx4 __attribute__((ext_vector_type(4)));

#define C_ELEMS (25165824ull)   // 8*6*128*128*32
#define NCONV   12288           // C_ELEMS / 8 / 256
#define FEAT_HALF (7680000ull)  // 8*30000*32
#define GTILES  469             // ceil(30000/64)
#define GHALF   (GTILES * 8)    // 3752 blocks per view-half

// Weight image layout (f16 element offsets)
#define OFF_W0A  0
#define OFF_WA   8192
#define OFF_HB   17408
#define OFF_FOLD 18432
#define OFF_F32  18560
#define IMG_F16  19456
// float region (floats): b0b0[0..31], fow[32..63], bb0[64..191], bb1[192..319], fob[320]

__device__ __align__(16) f16 g_chalf[C_ELEMS];
__device__ __align__(16) f16 g_feat[2 * FEAT_HALF];
__device__ __align__(16) f16 g_img[IMG_F16];

__device__ __forceinline__ int permrow(int m) {
    return 8 * ((m & 15) >> 2) + 4 * (m >> 4) + (m & 3);
}

__device__ __forceinline__ half2v cvt2(float a, float b) {
    return __builtin_bit_cast(half2v, __builtin_amdgcn_cvt_pkrtz(a, b));
}

__device__ __forceinline__ half8 pack8(floatx4 f0, floatx4 f1) {
    half2v h0 = cvt2(f0[0], f0[1]), h1 = cvt2(f0[2], f0[3]);
    half2v h2 = cvt2(f1[0], f1[1]), h3 = cvt2(f1[2], f1[3]);
    half4v q0 = __builtin_shufflevector(h0, h1, 0, 1, 2, 3);
    half4v q1 = __builtin_shufflevector(h2, h3, 0, 1, 2, 3);
    return __builtin_shufflevector(q0, q1, 0, 1, 2, 3, 4, 5, 6, 7);
}

__device__ __forceinline__ half8 relupack2(floatx4 a, floatx4 b) {
    half2v p0 = cvt2(fmaxf(a[0], 0.f), fmaxf(a[1], 0.f));
    half2v p1 = cvt2(fmaxf(a[2], 0.f), fmaxf(a[3], 0.f));
    half2v p2 = cvt2(fmaxf(b[0], 0.f), fmaxf(b[1], 0.f));
    half2v p3 = cvt2(fmaxf(b[2], 0.f), fmaxf(b[3], 0.f));
    half4v q0 = __builtin_shufflevector(p0, p1, 0, 1, 2, 3);
    half4v q1 = __builtin_shufflevector(p2, p3, 0, 1, 2, 3);
    return __builtin_shufflevector(q0, q1, 0, 1, 2, 3, 4, 5, 6, 7);
}

__device__ __forceinline__ half8 zext4(half4v lo) {
    const half4v zh = {};
    return __builtin_shufflevector(lo, zh, 0, 1, 2, 3, 4, 5, 6, 7);
}

__device__ __forceinline__ half8 splat8(float w) {
    f16 h = (f16)w;
    half8 v = {h, h, h, h, h, h, h, h};
    return v;
}

// Blocks 0..NCONV-1: c (f32) -> f16. Block NCONV: build the weight image.
__global__ __launch_bounds__(256) void convert_prep(
    const float* __restrict__ c,
    const float* __restrict__ fpw, const float* __restrict__ fpb,
    const float* __restrict__ b0w0, const float* __restrict__ b0b0,
    const float* __restrict__ b0w1, const float* __restrict__ b0b1,
    const float* __restrict__ b0ws, const float* __restrict__ bw0,
    const float* __restrict__ bb0, const float* __restrict__ bw1,
    const float* __restrict__ bb1, const float* __restrict__ fow,
    const float* __restrict__ fob)
{
    __shared__ floatx4 sp[8][32];
    const int tid = threadIdx.x;
    if (blockIdx.x < NCONV) {
        size_t i = ((size_t)blockIdx.x * 256 + tid) * 8;
        floatx4 f0 = *(const floatx4*)(c + i);
        floatx4 f1 = *(const floatx4*)(c + i + 4);
        *(half8*)(g_chalf + i) = pack8(f0, f1);
        return;
    }
    {   // fold partials
        int i = tid & 31, kc = tid >> 5;
        const float* wrow = b0ws + i * 256 + kc * 32;
        const float* pw = fpw + kc * 96;
        const float* pb = fpb + kc * 32;
        floatx4 acc = {};
        #pragma unroll 8
        for (int k = 0; k < 32; k++) {
            float w = wrow[k];
            acc[0] = fmaf(w, pw[k * 3 + 0], acc[0]);
            acc[1] = fmaf(w, pw[k * 3 + 1], acc[1]);
            acc[2] = fmaf(w, pw[k * 3 + 2], acc[2]);
            acc[3] = fmaf(w, pb[k], acc[3]);
        }
        sp[kc][i] = acc;
    }
    __syncthreads();
    {   // w0A
        int m = tid >> 3, seg = tid & 7;
        const float* src = b0w0 + permrow(m) * 256 + seg * 32;
        f16* dst = g_img + OFF_W0A + m * 256;
        int sw = m & 7;
        #pragma unroll
        for (int ci = 0; ci < 4; ci++) {
            int cidx = seg * 4 + ci;
            floatx4 f0 = *(const floatx4*)(src + ci * 8);
            floatx4 f1 = *(const floatx4*)(src + ci * 8 + 4);
            *(half8*)(dst + ((cidx ^ sw) << 3)) = pack8(f0, f1);
        }
    }
    for (int r = tid; r < 288; r += 256) {
        int mi = r >> 5, m = r & 31;
        int pm = permrow(m);
        const float* src;
        if (mi == 0) src = b0w1 + pm * 32;
        else {
            int mat = mi - 1, bi = mat >> 1;
            src = ((mat & 1) ? bw1 : bw0) + (bi * 32 + pm) * 32;
        }
        f16* dst = g_img + OFF_WA + mi * 1024 + m * 32;
        int sw = (m >> 1) & 3;
        #pragma unroll
        for (int ci = 0; ci < 4; ci++) {
            floatx4 f0 = *(const floatx4*)(src + ci * 8);
            floatx4 f1 = *(const floatx4*)(src + ci * 8 + 4);
            *(half8*)(dst + ((ci ^ sw) << 3)) = pack8(f0, f1);
        }
    }
    {   // hB
        int cch = tid >> 5, m = tid & 31;
        int h = cch * 32 + permrow(m);
        half2v a = cvt2(fpw[h * 3 + 0], fpw[h * 3 + 1]);
        half2v bq = cvt2(fpw[h * 3 + 2], fpb[h]);
        *(half4v*)(g_img + OFF_HB + tid * 4) = __builtin_shufflevector(a, bq, 0, 1, 2, 3);
    }
    float* fimg = (float*)(g_img + OFF_F32);
    if (tid < 32) {
        int pm = permrow(tid);
        floatx4 s = sp[0][pm];
        #pragma unroll
        for (int j = 1; j < 8; j++) s += sp[j][pm];
        half2v a = cvt2(s[0], s[1]);
        half2v bq = cvt2(s[2], s[3] + b0b1[pm]);
        *(half4v*)(g_img + OFF_FOLD + tid * 4) = __builtin_shufflevector(a, bq, 0, 1, 2, 3);
        fimg[tid] = b0b0[tid];
        fimg[32 + tid] = fow[tid];
    }
    if (tid >= 64 && tid < 192) {
        fimg[tid] = bb0[tid - 64];
        fimg[tid + 128] = bb1[tid - 64];
    }
    if (tid == 0) fimg[320] = fob[0];
}

// ---- Kernel A: gather, split by view-half so each XCD's working set is
// 3 views x 1.05 MB = 3.15 MB < 4 MiB L2 (full 6-view slab = 6.3 MB thrashed).
// Block layout: blockIdx = half*GHALF + tile*8 + b -> XCD (blockIdx&7) = b.
// One point-group per thread, 3 views: small footprint, 6 waves/SIMD.
__global__ __launch_bounds__(256, 6) void gather_kernel(
    const float* __restrict__ p, const float* __restrict__ Cm)
{
    __shared__ float s_cam[3][8];
    const int tid = threadIdx.x;
    const int half = blockIdx.x / GHALF;          // 0: views 0-2, 1: views 3-5
    const int rem = blockIdx.x - half * GHALF;
    const int tile = rem >> 3;
    const int b = rem & 7;

    if (tid < 3) {
        const float* cm = Cm + ((size_t)b * NL + half * 3 + tid) * 12;
        float denom = cm[9] + 0.05f;
        float s = 63.5f / (0.55f * denom);
        s_cam[tid][0] = cm[0] * s; s_cam[tid][1] = cm[1] * s; s_cam[tid][2] = cm[2] * s;
        s_cam[tid][3] = cm[3] * s; s_cam[tid][4] = cm[4] * s; s_cam[tid][5] = cm[5] * s;
    }
    __syncthreads();

    const int lane = tid & 63;
    const int wv = tid >> 6;
    const int q = lane >> 4;
    const int i16 = lane & 15;
    const f16* cqh = g_chalf + ((((size_t)b * NL + half * 3)) << 19) + q * 8;

    const int t = tile * 64 + wv * 16 + i16;
    const int tc = min(t, NT - 1);
    const float* pp = p + ((size_t)b * NT + tc) * 3;
    float px = pp[0], py = pp[1], pz = pp[2];

    half8 feh = {};
    #pragma unroll
    for (int l = 0; l < 3; l++) {
        float x = s_cam[l][0] * px + s_cam[l][1] * py + s_cam[l][2] * pz + 63.5f;
        float y = s_cam[l][3] * px + s_cam[l][4] * py + s_cam[l][5] * pz + 63.5f;
        float x0f = floorf(x), x1f = ceilf(x);
        float y0f = floorf(y), y1f = ceilf(y);
        float dxw = x1f - x, dyw = y1f - y;
        int x0 = min(max((int)x0f, 0), 127);
        int x1 = min(max((int)x1f, 0), 127);
        int y0 = min(max((int)y0f, 0), 127);
        int y1 = min(max((int)y1f, 0), 127);
        const f16* base = cqh + ((size_t)l << 19);
        half8 t11 = *(const half8*)(base + (size_t)((x0 << 7) + y0) * 32);
        half8 t12 = *(const half8*)(base + (size_t)((x1 << 7) + y0) * 32);
        half8 t21 = *(const half8*)(base + (size_t)((x0 << 7) + y1) * 32);
        half8 t22 = *(const half8*)(base + (size_t)((x1 << 7) + y1) * 32);
        float w11 = dxw * dyw;
        float w12 = (1.f - dxw) * dyw;
        float w21 = dxw * (1.f - dyw);
        float w22 = (1.f - dxw) * (1.f - dyw);
        feh += t11 * splat8(w11) + t12 * splat8(w12)
             + t21 * splat8(w21) + t22 * splat8(w22);
    }
    if (t < NT)
        *(half8*)(g_feat + half * FEAT_HALF + ((size_t)b * NT + t) * 32 + q * 8) = feh;
}

// ---- Kernel B: MLP. (256,2): unified arch+acc cap 256; caps <=168 spill
// 170-340 MB scratch (r3-r5/r9/r10). ----
__global__ __launch_bounds__(256, 2) void mlp_kernel(
    const float* __restrict__ p, float* __restrict__ out)
{
    __shared__ __align__(16) f16 s_img[IMG_F16];   // 38912 B
    const int tid = threadIdx.x;
    const int b = blockIdx.x & 7;
    const int tile = blockIdx.x >> 3;

    {
        const uint4* gsrc = (const uint4*)g_img;
        uint4* ldst = (uint4*)s_img;
        for (int i = tid; i < IMG_F16 / 8; i += 256) ldst[i] = gsrc[i];
    }
    __syncthreads();

    const int lane = tid & 63;
    const int wv = tid >> 6;
    const int q = lane >> 4;
    const int i16 = lane & 15;
    const int sw0 = i16 & 7;

    const f16* s_w0A = s_img + OFF_W0A;
    const f16* s_wA  = s_img + OFF_WA;
    const f16* s_hB  = s_img + OFF_HB;
    const float* sf  = (const float*)(s_img + OFF_F32);

    const f16* w0r0 = s_w0A + i16 * 256;
    const f16* w0r1 = s_w0A + (16 + i16) * 256;
    const int qsw = (q ^ ((i16 >> 1) & 3)) << 3;
    const int soff0 = i16 * 32 + qsw;
    const int soff1 = (16 + i16) * 32 + qsw;
    const f16* hB0 = s_hB + i16 * 4;
    const f16* hB1 = s_hB + (16 + i16) * 4;

    const half8 fA0 = zext4(*(const half4v*)(s_img + OFF_FOLD + i16 * 4));
    const half8 fA1 = zext4(*(const half4v*)(s_img + OFF_FOLD + (16 + i16) * 4));
    const floatx4 fw0 = *(const floatx4*)&sf[32 + q * 8];
    const floatx4 fw1 = *(const floatx4*)&sf[32 + q * 8 + 4];
    const floatx4 b00a = *(const floatx4*)&sf[q * 8];
    const floatx4 b00b = *(const floatx4*)&sf[q * 8 + 4];
    const float fobv = sf[320];

    #pragma unroll 1
    for (int g = 0; g < 2; g++) {
        const int t = tile * 128 + (g * 4 + wv) * 16 + i16;
        const int tc = min(t, NT - 1);
        const float* pp = p + ((size_t)b * NT + tc) * 3;
        float px = pp[0], py = pp[1], pz = pp[2];

        // feat = sum of the two view-half partials (coalesced b128 each)
        const f16* fbase = g_feat + ((size_t)b * NT + tc) * 32 + q * 8;
        half8 fh0 = *(const half8*)(fbase);
        half8 fh1 = *(const half8*)(fbase + FEAT_HALF);
        half8 feh = fh0 + fh1;
        floatx4 fe0 = floatx4{(float)feh[0], (float)feh[1], (float)feh[2], (float)feh[3]};
        floatx4 fe1 = floatx4{(float)feh[4], (float)feh[5], (float)feh[6], (float)feh[7]};

        half8 bp;
        {
            half2v xy = cvt2(px, py), z1 = cvt2(pz, 1.0f);
            half4v lo = __builtin_shufflevector(xy, z1, 0, 1, 2, 3);
            half8 full = zext4(lo);
            const half8 zh8 = {};
            bp = (q == 0) ? full : zh8;
        }

        floatx4 acc0 = b00a, acc1 = b00b;
        #pragma unroll 2
        for (int cch = 0; cch < 8; cch++) {
            half8 ha = zext4(*(const half4v*)(hB0 + cch * 128));
            half8 hb = zext4(*(const half4v*)(hB1 + cch * 128));
            floatx4 hz = {};
            floatx4 h0 = __builtin_amdgcn_mfma_f32_16x16x32_f16(ha, bp, hz, 0, 0, 0);
            floatx4 h1 = __builtin_amdgcn_mfma_f32_16x16x32_f16(hb, bp, hz, 0, 0, 0);
            half8 bf = relupack2(h0, h1);
            half8 a0 = *(const half8*)(w0r0 + ((((cch << 2) | q) ^ sw0) << 3));
            half8 a1 = *(const half8*)(w0r1 + ((((cch << 2) | q) ^ sw0) << 3));
            acc0 = __builtin_amdgcn_mfma_f32_16x16x32_f16(a0, bf, acc0, 0, 0, 0);
            acc1 = __builtin_amdgcn_mfma_f32_16x16x32_f16(a1, bf, acc1, 0, 0, 0);
        }

        floatx4 st0 = __builtin_amdgcn_mfma_f32_16x16x32_f16(fA0, bp, fe0, 0, 0, 0);
        floatx4 st1 = __builtin_amdgcn_mfma_f32_16x16x32_f16(fA1, bp, fe1, 0, 0, 0);
        {
            half8 bf = relupack2(acc0, acc1);
            half8 a0 = *(const half8*)(s_wA + soff0);
            half8 a1 = *(const half8*)(s_wA + soff1);
            st0 = __builtin_amdgcn_mfma_f32_16x16x32_f16(a0, bf, st0, 0, 0, 0);
            st1 = __builtin_amdgcn_mfma_f32_16x16x32_f16(a1, bf, st1, 0, 0, 0);
        }

        #pragma unroll
        for (int bk = 0; bk < 4; bk++) {
            const f16* w_a = s_wA + (1 + 2 * bk) * 1024;
            const f16* w_b = s_wA + (2 + 2 * bk) * 1024;
            floatx4 h0 = *(const floatx4*)&sf[64 + bk * 32 + q * 8];
            floatx4 h1 = *(const floatx4*)&sf[64 + bk * 32 + q * 8 + 4];
            {
                half8 bf = relupack2(st0, st1);
                half8 a0 = *(const half8*)(w_a + soff0);
                half8 a1 = *(const half8*)(w_a + soff1);
                h0 = __builtin_amdgcn_mfma_f32_16x16x32_f16(a0, bf, h0, 0, 0, 0);
                h1 = __builtin_amdgcn_mfma_f32_16x16x32_f16(a1, bf, h1, 0, 0, 0);
            }
            floatx4 d0 = *(const floatx4*)&sf[192 + bk * 32 + q * 8];
            floatx4 d1 = *(const floatx4*)&sf[192 + bk * 32 + q * 8 + 4];
            {
                half8 bf = relupack2(h0, h1);
                half8 a0 = *(const half8*)(w_b + soff0);
                half8 a1 = *(const half8*)(w_b + soff1);
                d0 = __builtin_amdgcn_mfma_f32_16x16x32_f16(a0, bf, d0, 0, 0, 0);
                d1 = __builtin_amdgcn_mfma_f32_16x16x32_f16(a1, bf, d1, 0, 0, 0);
            }
            st0 += d0 + fe0;
            st1 += d1 + fe1;
        }

        float o = 0.f;
        #pragma unroll
        for (int r = 0; r < 4; r++)
            o += fmaxf(st0[r], 0.f) * fw0[r] + fmaxf(st1[r], 0.f) * fw1[r];
        o += __shfl_xor(o, 16);
        o += __shfl_xor(o, 32);
        if (q == 0 && t < NT) out[(size_t)b * NT + t] = o + fobv;
    }
}

extern "C" void kernel_launch(void* const* d_in, const int* in_sizes, int n_in,
                              void* d_out, int out_size, void* d_ws, size_t ws_size,
                              hipStream_t stream) {
    const float* p    = (const float*)d_in[0];
    const float* c    = (const float*)d_in[2];
    const float* Cm   = (const float*)d_in[3];
    const float* fpw  = (const float*)d_in[4];
    const float* fpb  = (const float*)d_in[5];
    const float* b0w0 = (const float*)d_in[6];
    const float* b0b0 = (const float*)d_in[7];
    const float* b0w1 = (const float*)d_in[8];
    const float* b0b1 = (const float*)d_in[9];
    const float* b0ws = (const float*)d_in[10];
    const float* bw0  = (const float*)d_in[11];
    const float* bb0  = (const float*)d_in[12];
    const float* bw1  = (const float*)d_in[13];
    const float* bb1  = (const float*)d_in[14];
    const float* fow  = (const float*)d_in[15];
    const float* fob  = (const float*)d_in[16];

    convert_prep<<<NCONV + 1, 256, 0, stream>>>(c, fpw, fpb, b0w0, b0b0, b0w1, b0b1,
                                                b0ws, bw0, bb0, bw1, bb1, fow, fob);

    gather_kernel<<<2 * GHALF, 256, 0, stream>>>(p, Cm);

    dim3 grid(((NT + 127) / 128) * NB);  // 1880, 1-D for XCD swizzle
    mlp_kernel<<<grid, 256, 0, stream>>>(p, (float*)d_out);
}